// Round 11
// baseline (697.016 us; speedup 1.0000x reference)
//
#include <hip/hip_runtime.h>
#include <hip/hip_bf16.h>
#include <math.h>

// ---- problem constants (match reference setup) ----
constexpr int DD   = 768;    // feature dim
constexpr int NSUP = 1024;   // support rows (WAY*SHOT)
constexpr int NQQ  = 2048;   // queries
constexpr int NC   = 64;     // classes (way)
constexpr int SHOT = 16;
constexpr int RR   = 18;     // Woodbury rank = SHOT + 2
constexpr float REGP = 0.5f;
constexpr int DDS = DD * DD;
constexpr int NROWS = NQQ + NSUP + 1 + NC; // stacked rows: [Q; X; m; mu] -> transformed in place
constexpr int TRB  = 4;      // RHS rows per TRSM block (1 per wave)
constexpr int NTB  = (NROWS + TRB - 1) / TRB; // 785 trsm blocks -> ~3 blocks/CU
constexpr int NDB  = DD / 64; // 12 diagonal 64-blocks
constexpr int LW   = 384;    // TRSM leaf width
constexpr int LB   = LW / 64;// 6 leaf 64-blocks

// ---------------------------------------------------------------------------
// L = diag(|triu_diag|) + strictly-lower(triu_lower)
__global__ __launch_bounds__(256) void build_L(const float* __restrict__ tdiag,
                                               const float* __restrict__ tlow,
                                               float* __restrict__ Lm) {
    int idx = blockIdx.x * 256 + threadIdx.x;
    if (idx >= DDS) return;
    int i = idx / DD, j = idx % DD;
    float v = (i == j) ? fabsf(tdiag[i]) : (i > j ? tlow[idx] : 0.f);
    Lm[idx] = v;
}

// ---------------------------------------------------------------------------
// per-class: gather indices, compute mu_c into mmu rows 1..64; block0 copies m to row 0
__global__ __launch_bounds__(256) void class_stats(const float* __restrict__ Xs,
                                                   const float* __restrict__ m,
                                                   const int* __restrict__ labels,
                                                   const float* __restrict__ kappa,
                                                   float* __restrict__ mmu,
                                                   int* __restrict__ cls_idx,
                                                   int* __restrict__ cls_n) {
    int c = blockIdx.x;
    __shared__ int lidx[SHOT];
    __shared__ int lcount;
    if (threadIdx.x == 0) lcount = 0;
    __syncthreads();
    for (int n = threadIdx.x; n < NSUP; n += 256) {
        if (labels[n] == c) {
            int pos = atomicAdd(&lcount, 1);
            if (pos < SHOT) lidx[pos] = n;
        }
    }
    __syncthreads();
    int cnt = lcount < SHOT ? lcount : SHOT;
    if (threadIdx.x < SHOT) cls_idx[c * SHOT + threadIdx.x] = (threadIdx.x < cnt) ? lidx[threadIdx.x] : 0;
    if (threadIdx.x == 0) cls_n[c] = cnt;
    float kap = fabsf(kappa[0]) + 1e-6f;
    float fn = (float)cnt;
    float wm = kap / (kap + fn);
    float wx = 1.f / (kap + fn);
    if (c == 0) {
        for (int d = threadIdx.x; d < DD; d += 256) mmu[d] = m[d];
    }
    for (int d = threadIdx.x; d < DD; d += 256) {
        float s = 0.f;
        for (int t = 0; t < cnt; ++t) s += Xs[(size_t)lidx[t] * DD + d];
        mmu[(size_t)(1 + c) * DD + d] = wm * m[d] + wx * s;
    }
}

// ---------------------------------------------------------------------------
// invert each 64x64 lower-triangular diagonal block of L.
// Output TRANSPOSED for coalesced TRSM reads: DinvT[b][m][a] = (L_bb^{-1})[a][m]
__global__ __launch_bounds__(64) void diag_inv64(const float* __restrict__ Lm,
                                                 float* __restrict__ DinvT) {
    int b = blockIdx.x;
    __shared__ float lt[64][65];
    __shared__ float xt[64][65];
    int tid = threadIdx.x; // 64 threads
    for (int i = 0; i < 64; ++i) {
        lt[i][tid] = Lm[(size_t)(b * 64 + i) * DD + b * 64 + tid];
        xt[i][tid] = 0.f;
    }
    __syncthreads();
    int j = tid; // column j, independent per thread
    xt[j][j] = 1.f / lt[j][j];
    for (int i = j + 1; i < 64; ++i) {
        float s = 0.f;
        for (int k = j; k < i; ++k) s += lt[i][k] * xt[k][j];
        xt[i][j] = -s / lt[i][i];
    }
    __syncthreads();
    // DinvT[b*4096 + m*64 + a] = xt[a][m]
    for (int t = tid; t < 4096; t += 64)
        DinvT[(size_t)b * 4096 + t] = xt[t & 63][t >> 6];
}

// ---------------------------------------------------------------------------
// copy stacked [Qx; Xs; mmu] into Trows (float4), so TRSM can solve in place
__global__ __launch_bounds__(256) void copy_stack(const float* __restrict__ Qx,
                                                  const float* __restrict__ Xs,
                                                  const float* __restrict__ mmu,
                                                  float* __restrict__ Trows) {
    int f = blockIdx.x * 256 + threadIdx.x;       // float4 index
    if (f >= NROWS * (DD / 4)) return;
    int q = f / (DD / 4);
    int d4 = f % (DD / 4);
    const float* src;
    if (q < NQQ) src = Qx + (size_t)q * DD;
    else if (q < NQQ + NSUP) src = Xs + (size_t)(q - NQQ) * DD;
    else src = mmu + (size_t)(q - NQQ - NSUP) * DD;
    float4 v = *(const float4*)(src + d4 * 4);
    *(float4*)(Trows + (size_t)q * DD + d4 * 4) = v;
}

// ---------------------------------------------------------------------------
// Leaf TRSM over columns [c0, c0+LW): forward substitution in place on Trows.
// One block owns TRB=4 rows (1 per wave); leaf Y panel in LDS; LB=6 steps.
// Grid 785 blocks -> ~3 blocks/CU so phase latency overlaps across blocks.
__global__ __launch_bounds__(256) void leaf_trsm(float* __restrict__ Trows,
                                                 const float* __restrict__ Lm,
                                                 const float* __restrict__ DinvT,
                                                 int c0) {
    __shared__ float Ylds[LW * 5];    // 7.7 KB  (stride 5 -> 2-way-free banks)
    __shared__ float Lc[64][65];      // 16.6 KB staged 64x64 L chunk
    __shared__ float Ssh[64 * 5];     // 1.3 KB
    int tid = threadIdx.x;
    int a = tid & 63;                 // row within 64-block
    int g = tid >> 6;                 // wave id = rhs index within block
    int q = blockIdx.x * TRB + g;
    bool valid = q < NROWS;
    int qq = valid ? q : 0;
    int db0 = c0 >> 6;

    for (int r = 0; r < LB; ++r) {
        int r0 = r * 64;
        int gcol = c0 + r0;
        float s = 0.f;
        for (int kb = 0; kb < r; ++kb) {
            for (int t = tid; t < 4096; t += 256) {
                int i = t >> 6, k = t & 63;
                Lc[i][k] = Lm[(size_t)(gcol + i) * DD + c0 + kb * 64 + k];
            }
            __syncthreads();
            const float* ybase = &Ylds[(kb * 64) * 5 + g];
#pragma unroll 16
            for (int kk = 0; kk < 64; ++kk)
                s += Lc[a][kk] * ybase[kk * 5];      // wave-uniform broadcast
            __syncthreads();
        }
        // T[a] = rhs - S  (coalesced global read per wave)
        Ssh[a * 5 + g] = (valid ? Trows[(size_t)qq * DD + gcol + a] : 0.f) - s;
        __syncthreads();
        // y[a] = sum_m Dinv[a][m] * T[m];  DinvT layout [m*64 + a] -> coalesced
        float o = 0.f;
        const float* dptr = DinvT + (size_t)(db0 + r) * 4096 + a;
#pragma unroll 8
        for (int m = 0; m < 64; ++m)
            o += dptr[m * 64] * Ssh[m * 5 + g];
        Ylds[(r0 + a) * 5 + g] = o;
        if (valid) Trows[(size_t)qq * DD + gcol + a] = o;
        __syncthreads();   // Ylds + Ssh-reads settled before next step
    }
}

// ---------------------------------------------------------------------------
// C[M][Nn] (+/-)= A[M][K] * B[Nn][K]^T via atomicAdd (C pre-zeroed or live RHS).
// 128x64 tile, 8x4 acc/thread: 3x b128 LDS reads per 64 FLOP (0.75 B/FLOP).
// SPLIT: k-range split over blockIdx.z. NEG: subtract. lda/ldb/ldc row strides.
template <int SPLIT, bool NEG>
__global__ __launch_bounds__(256) void gemm_nt128(const float* __restrict__ A0,
                                                  const float* __restrict__ B,
                                                  float* __restrict__ Cc,
                                                  int M, int Nn, int K,
                                                  int lda, int ldb, int ldc) {
    __shared__ __align__(16) float As[32][132];
    __shared__ __align__(16) float Bs[32][68];
    int bm = blockIdx.x, bn = blockIdx.y, bz = blockIdx.z;
    int row0 = bm * 128, col0 = bn * 64;
    int tid = threadIdx.x;
    int tr = tid >> 4, tc = tid & 15;
    float acc[8][4] = {};
    int nch = K >> 5;
    int klo = 32 * ((bz * nch) / SPLIT);
    int khi = 32 * (((bz + 1) * nch) / SPLIT);
    for (int k0 = klo; k0 < khi; k0 += 32) {
        for (int t = tid; t < 128 * 32; t += 256) {
            int r = t >> 5, kk = t & 31;
            int ar = row0 + r;
            As[kk][r] = (ar < M) ? A0[(size_t)ar * lda + k0 + kk] : 0.f;
        }
        for (int t = tid; t < 64 * 32; t += 256) {
            int r = t >> 5, kk = t & 31;
            int br = col0 + r;
            Bs[kk][r] = (br < Nn) ? B[(size_t)br * ldb + k0 + kk] : 0.f;
        }
        __syncthreads();
#pragma unroll
        for (int kk = 0; kk < 32; ++kk) {
            float4 a0v = *(const float4*)(&As[kk][tr * 8]);
            float4 a1v = *(const float4*)(&As[kk][tr * 8 + 4]);
            float4 bv  = *(const float4*)(&Bs[kk][tc * 4]);
            float a[8] = {a0v.x, a0v.y, a0v.z, a0v.w, a1v.x, a1v.y, a1v.z, a1v.w};
            float b[4] = {bv.x, bv.y, bv.z, bv.w};
#pragma unroll
            for (int x = 0; x < 8; ++x)
#pragma unroll
                for (int y = 0; y < 4; ++y) acc[x][y] += a[x] * b[y];
        }
        __syncthreads();
    }
#pragma unroll
    for (int x = 0; x < 8; ++x) {
        int r = row0 + tr * 8 + x;
        if (r >= M) continue;
#pragma unroll
        for (int y = 0; y < 4; ++y) {
            int cc2 = col0 + tc * 4 + y;
            if (cc2 < Nn) atomicAdd(&Cc[(size_t)r * ldc + cc2], NEG ? -acc[x][y] : acc[x][y]);
        }
    }
}

// ---------------------------------------------------------------------------
// Vt row (c*18+i): i<16 -> TX[idx], i==16 -> sqrt(kap)*Tm, i==17 -> sqrt(kap+Nc)*Tmu_c
__global__ __launch_bounds__(256) void build_V(const float* __restrict__ Trows,
                                               const int* __restrict__ cls_idx,
                                               const int* __restrict__ cls_n,
                                               const float* __restrict__ kappa,
                                               float* __restrict__ Vt) {
    int row = blockIdx.x;
    int c = row / RR, i = row % RR;
    int cnt = cls_n[c];
    float kap = fabsf(kappa[0]) + 1e-6f;
    size_t srow;
    float sc = 1.f;
    if (i < SHOT) {
        if (i >= cnt) {
            for (int d = threadIdx.x; d < DD; d += 256) Vt[(size_t)row * DD + d] = 0.f;
            return;
        }
        srow = (size_t)NQQ + cls_idx[c * SHOT + i];
    } else if (i == SHOT) {
        srow = NQQ + NSUP;
        sc = sqrtf(kap);
    } else {
        srow = (size_t)NQQ + NSUP + 1 + c;
        sc = sqrtf(kap + (float)cnt);
    }
    for (int d = threadIdx.x; d < DD; d += 256)
        Vt[(size_t)row * DD + d] = sc * Trows[srow * DD + d];
}

// ---------------------------------------------------------------------------
// per class: M = J + Vt Vt^T (fp64), invert (GJ w/ pivoting, fp64), h, consts.
__global__ __launch_bounds__(256) void build_M(const float* __restrict__ Trows,
                                               const float* __restrict__ mmu,
                                               const float* __restrict__ Vt,
                                               const float* __restrict__ tdiag,
                                               const float* __restrict__ kappa,
                                               const float* __restrict__ nu,
                                               const int* __restrict__ cls_n,
                                               float* __restrict__ consts,
                                               float* __restrict__ hbuf,
                                               float* __restrict__ MinvO) {
    int c = blockIdx.x;
    __shared__ double Md[RR][RR];
    __shared__ double aug[RR][2 * RR];
    __shared__ double colk[RR];
    __shared__ double red[4];
    __shared__ double gj_logdet;
    __shared__ float hs[RR];
    __shared__ float ng2t_s, mu2_s;
    int tid = threadIdx.x;
    int wave = tid >> 6, lane = tid & 63;
    const float* Vc = Vt + (size_t)c * RR * DD;
    const float* Tmu = Trows + (size_t)(NQQ + NSUP + 1 + c) * DD;
    const float* mu_raw = mmu + (size_t)(1 + c) * DD;

    for (int p = wave; p < RR * RR + RR + 2; p += 4) {
        const float *va, *vb;
        if (p < RR * RR) {
            int i = p / RR, j = p % RR;
            if (i > j) continue;
            va = Vc + (size_t)i * DD; vb = Vc + (size_t)j * DD;
        } else if (p < RR * RR + RR) {
            va = Vc + (size_t)(p - RR * RR) * DD; vb = Tmu;
        } else if (p == RR * RR + RR) {
            va = Tmu; vb = Tmu;
        } else {
            va = mu_raw; vb = mu_raw;
        }
        double s = 0.0;
        for (int d = lane; d < DD; d += 64) s += (double)va[d] * (double)vb[d];
        for (int off = 32; off; off >>= 1) s += __shfl_down(s, off);
        if (lane == 0) {
            if (p < RR * RR) { int i = p / RR, j = p % RR; Md[i][j] = s; Md[j][i] = s; }
            else if (p < RR * RR + RR) hs[p - RR * RR] = (float)s;
            else if (p == RR * RR + RR) ng2t_s = (float)s;
            else mu2_s = (float)s;
        }
    }
    double sl = 0.0;
    for (int k = tid; k < DD; k += 256) sl += log((double)fabsf(tdiag[k]));
    for (int off = 32; off; off >>= 1) sl += __shfl_down(sl, off);
    if (lane == 0) red[wave] = sl;
    __syncthreads();

    if (tid == 0) {
        for (int i = 0; i < RR - 1; ++i) Md[i][i] += 1.0;
        Md[RR - 1][RR - 1] -= 1.0;
        gj_logdet = 0.0;
    }
    __syncthreads();
    for (int t = tid; t < RR * 2 * RR; t += 256) {
        int r2 = t / (2 * RR), j2 = t % (2 * RR);
        aug[r2][j2] = (j2 < RR) ? Md[r2][j2] : ((j2 - RR == r2) ? 1.0 : 0.0);
    }
    __syncthreads();
    for (int k = 0; k < RR; ++k) {
        if (tid == 0) {
            int piv = k; double best = fabs(aug[k][k]);
            for (int r2 = k + 1; r2 < RR; ++r2) {
                double v = fabs(aug[r2][k]);
                if (v > best) { best = v; piv = r2; }
            }
            if (piv != k) {
                for (int j2 = 0; j2 < 2 * RR; ++j2) {
                    double tmp = aug[k][j2]; aug[k][j2] = aug[piv][j2]; aug[piv][j2] = tmp;
                }
            }
            double pv = aug[k][k];
            gj_logdet += log(fabs(pv));
            double inv = 1.0 / pv;
            for (int j2 = 0; j2 < 2 * RR; ++j2) aug[k][j2] *= inv;
        }
        __syncthreads();
        if (tid < RR) colk[tid] = (tid == k) ? 0.0 : aug[tid][k];
        __syncthreads();
        for (int t = tid; t < RR * 2 * RR; t += 256) {
            int r2 = t / (2 * RR), j2 = t % (2 * RR);
            if (r2 != k) aug[r2][j2] -= colk[r2] * aug[k][j2];
        }
        __syncthreads();
    }
    if (tid == 0) {
        double sumlog = red[0] + red[1] + red[2] + red[3];
        double kap = fabs((double)kappa[0]) + 1e-6;
        double nu_ = fmax((double)nu[0], (double)(DD - 1) + 1e-6);
        double fn = (double)cls_n[c];
        double common = nu_ + fn + 1.0 - (double)DD;
        double scale = (kap + fn + 1.0) / (common * (kap + fn));
        double logdet_sigma = (double)DD * log(scale) + 2.0 * sumlog + gj_logdet;
        double bias = lgamma(0.5 * (common + DD)) - lgamma(0.5 * common)
                    - 0.5 * DD * log(common) - 0.5 * logdet_sigma;
        consts[c * 8 + 0] = (float)((1.0 - (double)REGP) / scale);
        consts[c * 8 + 1] = (float)common;
        consts[c * 8 + 2] = (float)(0.5 * (common + DD));
        consts[c * 8 + 3] = (float)bias;
        consts[c * 8 + 4] = (float)(1.0 / sqrt(kap + fn));
        consts[c * 8 + 5] = ng2t_s;
        consts[c * 8 + 6] = mu2_s;
        consts[c * 8 + 7] = 0.f;
    }
    __syncthreads();
    for (int t = tid; t < RR * RR; t += 256)
        MinvO[(size_t)c * RR * RR + t] = (float)aug[t / RR][RR + t % RR];
    if (tid < RR) hbuf[c * RR + tid] = hs[tid];
}

// ---------------------------------------------------------------------------
__global__ __launch_bounds__(256) void query_norms(const float* __restrict__ Qx,
                                                   const float* __restrict__ Trows,
                                                   float* __restrict__ q2,
                                                   float* __restrict__ nq2t) {
    int q = blockIdx.x * 4 + (threadIdx.x >> 6);
    int lane = threadIdx.x & 63;
    float s1 = 0.f, s2 = 0.f;
    for (int d = lane; d < DD; d += 64) {
        float a = Qx[(size_t)q * DD + d]; s1 += a * a;
        float b = Trows[(size_t)q * DD + d]; s2 += b * b;
    }
    for (int off = 32; off; off >>= 1) { s1 += __shfl_down(s1, off); s2 += __shfl_down(s2, off); }
    if (lane == 0) { q2[q] = s1; nq2t[q] = s2; }
}

// ---------------------------------------------------------------------------
// PT layout: PT[(c*RR+i)*NQQ + q]  (coalesced across q). dotqmuT[c*NQQ + q].
__global__ __launch_bounds__(256) void final_kernel(const float* __restrict__ PT,
                                                    const float* __restrict__ dotqmuT,
                                                    const float* __restrict__ q2,
                                                    const float* __restrict__ nq2t,
                                                    const float* __restrict__ consts,
                                                    const float* __restrict__ hbuf,
                                                    const float* __restrict__ Minv,
                                                    float* __restrict__ out) {
    int c = blockIdx.x, qt = blockIdx.y;
    __shared__ float Ms[RR][RR];
    __shared__ float hlds[RR];
    __shared__ float cs[8];
    int tid = threadIdx.x;
    for (int t = tid; t < RR * RR; t += 256) Ms[t / RR][t % RR] = Minv[(size_t)c * RR * RR + t];
    if (tid < RR) hlds[tid] = hbuf[c * RR + tid];
    if (tid < 8) cs[tid] = consts[c * 8 + tid];
    __syncthreads();
    int q = qt * 256 + tid;
    const float* Pc = PT + (size_t)c * RR * NQQ + q;
    float p[RR];
    float p17raw = Pc[(size_t)(RR - 1) * NQQ];
#pragma unroll
    for (int i = 0; i < RR; ++i) p[i] = Pc[(size_t)i * NQQ] - hlds[i];
    float quad = 0.f;
#pragma unroll
    for (int i = 0; i < RR; ++i) {
        float t = 0.f;
#pragma unroll
        for (int j = 0; j < RR; ++j) t += Ms[i][j] * p[j];
        quad += p[i] * t;
    }
    float w1 = cs[0], common = cs[1], coef = cs[2], bias = cs[3];
    float inv_s17 = cs[4], ng2t = cs[5], mu2 = cs[6];
    float Gu2 = nq2t[q] - 2.f * p17raw * inv_s17 + ng2t;
    float u2 = q2[q] - 2.f * dotqmuT[(size_t)c * NQQ + q] + mu2;
    float dist = w1 * (Gu2 - quad) + REGP * u2;
    out[(size_t)q * NC + c] = bias - coef * log1pf(dist / common);
}

// ---------------------------------------------------------------------------
extern "C" void kernel_launch(void* const* d_in, const int* in_sizes, int n_in,
                              void* d_out, int out_size, void* d_ws, size_t ws_size,
                              hipStream_t stream) {
    const float* Xs    = (const float*)d_in[0];
    const float* Qx    = (const float*)d_in[1];
    const float* m     = (const float*)d_in[2];
    const float* kappa = (const float*)d_in[3];
    const float* nu    = (const float*)d_in[4];
    const float* tdiag = (const float*)d_in[5];
    const float* tlow  = (const float*)d_in[6];
    const int* labels  = (const int*)d_in[7];
    float* out = (float*)d_out;

    float* ws = (float*)d_ws;
    float* Lm      = ws;                                  // D*D
    float* mmu     = Lm + DDS;                            // (NC+1)*D  [m; mu_0..63]
    float* DinvT   = mmu + (size_t)(NC + 1) * DD;         // 12*64*64 (transposed diag inverses)
    float* Trows   = DinvT + (size_t)NDB * 64 * 64;       // NROWS*D (stacked rhs -> solved in place)
    float* Vt      = Trows + (size_t)NROWS * DD;          // NC*RR*D
    float* PT      = Vt + (size_t)NC * RR * DD;           // (NC*RR) x NQ  (transposed P)
    float* dotqmuT = PT + (size_t)NC * RR * NQQ;          // NC x NQ (contiguous after PT)
    float* q2      = dotqmuT + (size_t)NC * NQQ;          // NQ
    float* nq2t    = q2 + NQQ;                            // NQ
    float* consts  = nq2t + NQQ;                          // NC*8
    float* hbuf    = consts + NC * 8;                     // NC*RR
    float* MinvB   = hbuf + NC * RR;                      // NC*RR*RR
    int* cls_idx   = (int*)(MinvB + (size_t)NC * RR * RR);// NC*SHOT
    int* cls_n     = cls_idx + NC * SHOT;                 // NC

    // zero the atomic-accumulated outputs (PT + dotqmuT contiguous)
    hipMemsetAsync(PT, 0, ((size_t)NC * RR * NQQ + (size_t)NC * NQQ) * sizeof(float), stream);

    build_L<<<(DDS + 255) / 256, 256, 0, stream>>>(tdiag, tlow, Lm);
    class_stats<<<NC, 256, 0, stream>>>(Xs, m, labels, kappa, mmu, cls_idx, cls_n);
    diag_inv64<<<NDB, 64, 0, stream>>>(Lm, DinvT);
    copy_stack<<<(NROWS * (DD / 4) + 255) / 256, 256, 0, stream>>>(Qx, Xs, mmu, Trows);
    // two-level blocked TRSM: leaf solve | trailing GEMM update | leaf solve
    leaf_trsm<<<NTB, 256, 0, stream>>>(Trows, Lm, DinvT, 0);
    gemm_nt128<2, true><<<dim3((NROWS + 127) / 128, LW / 64, 2), 256, 0, stream>>>(
        Trows, Lm + (size_t)LW * DD, Trows + LW, NROWS, LW, LW, DD, DD, DD);
    leaf_trsm<<<NTB, 256, 0, stream>>>(Trows, Lm, DinvT, LW);
    build_V<<<NC * RR, 256, 0, stream>>>(Trows, cls_idx, cls_n, kappa, Vt);
    build_M<<<NC, 256, 0, stream>>>(Trows, mmu, Vt, tdiag, kappa, nu, cls_n, consts, hbuf, MinvB);
    query_norms<<<NQQ / 4, 256, 0, stream>>>(Qx, Trows, q2, nq2t);
    // PT = Vt @ Trows^T  (M=1152, N=2048) -> coalesced final reads
    gemm_nt128<2, false><<<dim3((NC * RR) / 128, NQQ / 64, 2), 256, 0, stream>>>(
        Vt, Trows, PT, NC * RR, NQQ, DD, DD, DD, NQQ);
    // dotqmuT = mu @ Qx^T  (M=64, N=2048)
    gemm_nt128<4, false><<<dim3(1, NQQ / 64, 4), 256, 0, stream>>>(
        mmu + DD, Qx, dotqmuT, NC, NQQ, DD, DD, DD, NQQ);
    final_kernel<<<dim3(NC, NQQ / 256), 256, 0, stream>>>(PT, dotqmuT, q2, nq2t, consts, hbuf, MinvB, out);
}